// Round 15
// baseline (471.638 us; speedup 1.0000x reference)
//
#include <hip/hip_runtime.h>
#include <hip/hip_bf16.h>
#include <stdint.h>

#define Bb 32
#define Lx 512
#define Cc 256
#define Tt 4
#define HID 1024
#define RR (Bb*Lx)          // 16384 logical rows (b*L+l)
#define MRf (RR*Tt)         // 65536 interleaved rows (r*4+t)

typedef int i32x4 __attribute__((ext_vector_type(4)));

// ---------------- async global->LDS, 16B per lane
__device__ __forceinline__ void gl16(const void* g, void* l) {
    __builtin_amdgcn_global_load_lds(
        (const __attribute__((address_space(1))) unsigned int*)g,
        (__attribute__((address_space(3))) unsigned int*)l, 16, 0, 0);
}
__device__ __forceinline__ void blockbar() {
    asm volatile("" ::: "memory");
    __builtin_amdgcn_s_barrier();
    asm volatile("" ::: "memory");
}

// ---------------- per-row weight quantization: w*2^s_row = i1*2^14 + i2*2^7 + i3
__global__ void quant_rows(const float* __restrict__ enc_w,
                           const float* __restrict__ cell_w,
                           int8_t* __restrict__ qEnc, int8_t* __restrict__ qC0,
                           int8_t* __restrict__ qC1, float* __restrict__ invN) {
    const int gw   = (blockIdx.x * blockDim.x + threadIdx.x) >> 6;  // 0..3071
    const int lane = threadIdx.x & 63;
    const int mat  = gw >> 10;           // 0 enc, 1 cell0, 2 cell1
    const int row  = gw & 1023;
    const int Kk   = (mat == 0) ? Cc : HID;
    const float* w = (mat == 0) ? enc_w + (size_t)row * Cc
                                : cell_w + (size_t)(mat-1)*HID*HID + (size_t)row * HID;
    int8_t* q = ((mat == 0) ? qEnc : (mat == 1 ? qC0 : qC1)) + (size_t)row * Kk;
    const size_t nElem = (size_t)HID * Kk;

    float m = 0.0f;
    for (int k = lane; k < Kk; k += 64) m = fmaxf(m, fabsf(w[k]));
    #pragma unroll
    for (int o = 32; o; o >>= 1) m = fmaxf(m, __shfl_xor(m, o));
    m = fmaxf(m, 1e-20f);
    float sp = exp2f(floorf(log2f(126.0f * 16384.0f / m)));
    if (m * sp > 126.0f * 16384.0f) sp *= 0.5f;     // guard log2 boundary
    if (lane == 0) invN[mat*HID + row] = 1.0f / sp;
    for (int k = lane; k < Kk; k += 64) {
        float v  = rintf(w[k] * sp);                // |v| <= 126*2^14, integer-exact in f32
        float i1 = rintf(v * (1.0f/16384.0f));      // |i1| <= 126
        float r1 = v - i1 * 16384.0f;               // |r1| <= 2^13, exact
        float i2 = rintf(r1 * (1.0f/128.0f));       // |i2| <= 64
        float r2 = r1 - i2 * 128.0f;                // |r2| <= 64, exact
        q[k]           = (int8_t)i1;
        q[nElem + k]   = (int8_t)i2;
        q[2*nElem + k] = (int8_t)r2;
    }
}

__global__ void zero_out(float* p, int n) {
    int i = blockIdx.x * 256 + threadIdx.x;
    if (i < n) p[i] = 0.0f;
}

// ---------------- Stage 1: conv(K=3 over L) + BN + LIF -> i8 spikes, rows r*4+t
__global__ void conv_bn_lif(const float* __restrict__ x,
                            const float* __restrict__ cw, const float* __restrict__ cb,
                            const float* __restrict__ g,  const float* __restrict__ be,
                            const float* __restrict__ mu, const float* __restrict__ var,
                            int8_t* __restrict__ spk) {   // [RR*4][Cc]
    int idx = blockIdx.x * blockDim.x + threadIdx.x;      // over B*L*C/4
    if (idx >= Bb*Lx*Cc/4) return;
    int bl = idx / (Cc/4);
    int c4 = (idx % (Cc/4)) * 4;
    int l  = bl % Lx;
    float4 x0 = *(const float4*)(x + (size_t)bl*Cc + c4);
    float4 xm = (l > 0)    ? *(const float4*)(x + (size_t)bl*Cc + c4 - Cc) : float4{0,0,0,0};
    float4 xp = (l < Lx-1) ? *(const float4*)(x + (size_t)bl*Cc + c4 + Cc) : float4{0,0,0,0};
    float v0=0, v1=0, v2=0, v3=0;
    #pragma unroll
    for (int t = 0; t < Tt; ++t) {
        float w0 = cw[t*3+0], w1 = cw[t*3+1], w2 = cw[t*3+2];
        float inv = g[t] / sqrtf(var[t] + 1e-5f);
        float off = (cb[t] - mu[t]) * inv + be[t];
        float y0 = (w0*xm.x + w1*x0.x + w2*xp.x) * inv + off;
        float y1 = (w0*xm.y + w1*x0.y + w2*xp.y) * inv + off;
        float y2 = (w0*xm.z + w1*x0.z + w2*xp.z) * inv + off;
        float y3 = (w0*xm.w + w1*x0.w + w2*xp.w) * inv + off;
        v0 = v0 + (y0 - v0)*0.5f;  v1 = v1 + (y1 - v1)*0.5f;
        v2 = v2 + (y2 - v2)*0.5f;  v3 = v3 + (y3 - v3)*0.5f;
        float s0 = (v0 >= 1.0f) ? 1.0f : 0.0f;  float s1 = (v1 >= 1.0f) ? 1.0f : 0.0f;
        float s2 = (v2 >= 1.0f) ? 1.0f : 0.0f;  float s3 = (v3 >= 1.0f) ? 1.0f : 0.0f;
        uchar4 pk = { (uint8_t)s0, (uint8_t)s1, (uint8_t)s2, (uint8_t)s3 };
        *(uchar4*)(spk + (size_t)(bl*4 + t)*Cc + c4) = pk;
        v0 *= (1.0f - s0);  v1 *= (1.0f - s1);  v2 *= (1.0f - s2);  v3 *= (1.0f - s3);
    }
}

// ---------------- i8 3-pass GEMM: deep pipeline (counted vmcnt) x 2-phase body
// Tile 256x256, BK=64, 8 waves (2M x 4N), wave tile 128x64 (acc[8][4]=128 AGPR).
// 4 LDS bufs x 32KB; prefetch 3; vmcnt(8) ladder at tile top ONLY (never drains
// the in-flight prefetch -- R12's bug). Tile body = 2 phases x 16 MFMA (m-halves,
// distinct acc): {frag reads, 2 sweeps, bar, lgkm0, sched_bar, prio1, 16 MFMA,
// prio0, bar} -- the m201 discipline at correct granularity.
// acc = (acc1*128 + acc2)*128 + acc3 exact in i32 (|acc| < 2^31, per-row scale).
template<int K, bool FINAL>
__global__ __launch_bounds__(512, 2)
void gemm_lif(const int8_t* __restrict__ A,
              const int8_t* __restrict__ Wq,      // [3 comps][HID][K]
              const float* __restrict__ invN,     // [HID] per-row 2^-s
              const float* __restrict__ bias,
              int8_t* __restrict__ spk_out, float* __restrict__ out_mean,
              float* __restrict__ out_sum) {
    constexpr int KT  = K / 64;           // tiles per component pass
    constexpr int NKT = 3 * KT;           // three fixed-point component passes
    __shared__ int8_t lds[4 * 32768];     // 4 bufs x (A 16KB + B 16KB)

    const int tid  = threadIdx.x;
    const int lane = tid & 63;
    const int wid  = tid >> 6;
    const int wm   = wid >> 2;        // 0..1
    const int wn   = wid & 3;         // 0..3
    // XCD-chunked decode (1024 blocks): xcd = bid&7 owns 32 m-panels; within an
    // XCD, n varies fastest (4 n-blocks reuse one L2-resident A panel).
    const int bid  = blockIdx.x;
    const int idx_ = bid >> 3;                     // 0..127
    const int n0   = (idx_ & 3) * 256;
    const int m0   = ((bid & 7) * 32 + (idx_ >> 2)) * 256;
    const int fr   = lane & 15;
    const int lq   = lane >> 4;
    const int swq  = (lq ^ ((fr >> 1) & 3)) * 16;   // conflict-free phys byte slot in 64B row
    const int srow = tid >> 2;                      // staging row (0..127)
    const int sl   = (tid & 3) ^ ((srow >> 1) & 3); // pre-swizzled source slot

    i32x4 acc[8][4] = {};

    // ---- full-tile stage (prologue only): A 256 rows + B 256 rows, 4 gl16/thread
    auto stage = [&](int t, int8_t* buf) {
        const int8_t* Wc = Wq + (size_t)(t / KT) * HID * K;
        const int ko = (t % KT) * 64;
        gl16(A  + (size_t)(m0 +       srow) * K + ko + sl*16, buf +         tid*16);
        gl16(A  + (size_t)(m0 + 128 + srow) * K + ko + sl*16, buf +  8192 + tid*16);
        gl16(Wc + (size_t)(n0 +       srow) * K + ko + sl*16, buf + 16384 + tid*16);
        gl16(Wc + (size_t)(n0 + 128 + srow) * K + ko + sl*16, buf + 24576 + tid*16);
    };

    // ---- prologue: stage tiles 0,1,2 into bufs 0,1,2
    stage(0, &lds[0]);
    stage(1, &lds[32768]);
    stage(2, &lds[65536]);

    #pragma unroll 1
    for (int kt = 0; kt < NKT; ++kt) {
        if (kt == KT || kt == 2*KT) {     // component boundary: shift accumulated value
            #pragma unroll
            for (int i = 0; i < 8; ++i)
                #pragma unroll
                for (int j = 0; j < 4; ++j)
                    acc[i][j] *= 128;
        }
        if (kt < NKT-2)       asm volatile("s_waitcnt vmcnt(8)" ::: "memory");
        else if (kt == NKT-2) asm volatile("s_waitcnt vmcnt(4)" ::: "memory");
        else                  asm volatile("s_waitcnt vmcnt(0)" ::: "memory");
        blockbar();                       // tile kt landed for all waves

        const int cb  = (kt & 3) * 32768;
        const bool pre = (kt + 3 < NKT);
        int8_t* pbuf  = &lds[((kt + 3) & 3) * 32768];
        const int tp  = kt + 3;
        const int kop = (tp % KT) * 64;
        const int8_t* Wp = Wq + (size_t)(tp / KT) * HID * K;

        i32x4 af[8], bf[4];

        // ===== phase 1: af[0..3]+bf[0..3] reads | A sweeps (kt+3) | 16 MFMA (i=0..3)
        #pragma unroll
        for (int i = 0; i < 4; ++i)
            af[i] = *(const i32x4*)&lds[cb + (wm*128 + i*16 + fr)*64 + swq];
        #pragma unroll
        for (int j = 0; j < 4; ++j)
            bf[j] = *(const i32x4*)&lds[cb + 16384 + (wn*64 + j*16 + fr)*64 + swq];
        if (pre) {
            gl16(A + (size_t)(m0 +       srow) * K + kop + sl*16, pbuf +        tid*16);
            gl16(A + (size_t)(m0 + 128 + srow) * K + kop + sl*16, pbuf + 8192 + tid*16);
        }
        blockbar();
        asm volatile("s_waitcnt lgkmcnt(0)" ::: "memory");
        __builtin_amdgcn_sched_barrier(0);
        __builtin_amdgcn_s_setprio(1);
        #pragma unroll
        for (int i = 0; i < 4; ++i)
            #pragma unroll
            for (int j = 0; j < 4; ++j)
                acc[i][j] = __builtin_amdgcn_mfma_i32_16x16x64_i8(af[i], bf[j], acc[i][j], 0, 0, 0);
        __builtin_amdgcn_s_setprio(0);
        blockbar();

        // ===== phase 2: af[4..7] reads | B sweeps (kt+3) | 16 MFMA (i=4..7)
        #pragma unroll
        for (int i = 4; i < 8; ++i)
            af[i] = *(const i32x4*)&lds[cb + (wm*128 + i*16 + fr)*64 + swq];
        if (pre) {
            gl16(Wp + (size_t)(n0 +       srow) * K + kop + sl*16, pbuf + 16384 + tid*16);
            gl16(Wp + (size_t)(n0 + 128 + srow) * K + kop + sl*16, pbuf + 24576 + tid*16);
        }
        blockbar();
        asm volatile("s_waitcnt lgkmcnt(0)" ::: "memory");
        __builtin_amdgcn_sched_barrier(0);
        __builtin_amdgcn_s_setprio(1);
        #pragma unroll
        for (int i = 4; i < 8; ++i)
            #pragma unroll
            for (int j = 0; j < 4; ++j)
                acc[i][j] = __builtin_amdgcn_mfma_i32_16x16x64_i8(af[i], bf[j], acc[i][j], 0, 0, 0);
        __builtin_amdgcn_s_setprio(0);
        // next tile-top vmcnt+bar closes this tile
    }

    // ---- epilogue: per-lane LIF over 4 acc regs (= 4 timesteps of one row)
    float bs[4], iv[4], msum[4] = {0,0,0,0};
    #pragma unroll
    for (int j = 0; j < 4; ++j) {
        int n = n0 + wn*64 + j*16 + fr;
        bs[j] = bias[n];
        iv[j] = invN[n];
    }
    const int rowq = lq * 4;
    #pragma unroll
    for (int i = 0; i < 8; ++i) {
        int rowLocal = m0 + wm*128 + i*16 + rowq;   // t=0 row; rows rowLocal..+3 = t 0..3
        int r = rowLocal >> 2;
        #pragma unroll
        for (int j = 0; j < 4; ++j) {
            int n = n0 + wn*64 + j*16 + fr;
            float v = 0.0f, ssum = 0.0f;
            #pragma unroll
            for (int t = 0; t < 4; ++t) {
                float xv = (float)acc[i][j][t] * iv[j] + bs[j];
                v = v + (xv - v) * 0.5f;
                float s = (v >= 1.0f) ? 1.0f : 0.0f;
                if constexpr (FINAL) ssum += s;
                else spk_out[(size_t)(rowLocal + t) * HID + n] = (int8_t)s;
                v = v * (1.0f - s);
            }
            if constexpr (FINAL) {
                out_mean[(size_t)r * HID + n] = ssum * 0.25f;
                msum[j] += ssum;            // integer <= 4, exact
            }
        }
    }
    if constexpr (FINAL) {
        // fused mean over L: reduce msum over lq -> one dyadic atomicAdd per (fr,j).
        // All partials are multiples of 2^-11 and < 2 -> exact f32, order-independent.
        const int b = m0 >> 11;             // all 64 r's of this block share b
        #pragma unroll
        for (int j = 0; j < 4; ++j) {
            float v = msum[j];
            v += __shfl_xor(v, 16);
            v += __shfl_xor(v, 32);
            if (lq == 0) {
                int n = n0 + wn*64 + j*16 + fr;
                atomicAdd(out_sum + (size_t)b * HID + n, v * (0.25f / 512.0f));
            }
        }
    }
}

extern "C" void kernel_launch(void* const* d_in, const int* in_sizes, int n_in,
                              void* d_out, int out_size, void* d_ws, size_t ws_size,
                              hipStream_t stream) {
    const float* x      = (const float*)d_in[0];
    const float* cw     = (const float*)d_in[1];
    const float* cb     = (const float*)d_in[2];
    const float* g      = (const float*)d_in[3];
    const float* be     = (const float*)d_in[4];
    const float* mu     = (const float*)d_in[5];
    const float* var    = (const float*)d_in[6];
    const float* enc_w  = (const float*)d_in[7];
    const float* enc_b  = (const float*)d_in[8];
    const float* cell_w = (const float*)d_in[9];
    const float* cell_b = (const float*)d_in[10];

    float* out1 = (float*)d_out;                    // [RR][HID]
    float* out2 = out1 + (size_t)RR * HID;          // [B][HID]

    // ---- ws layout (~135 MB; 144 MB proven available)
    uint8_t* ws = (uint8_t*)d_ws;
    int8_t* X = (int8_t*)ws;                               // 64 MB (spk1 16MB -> layer2 out)
    int8_t* Y = (int8_t*)(ws + (size_t)64*1024*1024);      // 64 MB (layer1 out)
    int8_t* qEnc = (int8_t*)(ws + (size_t)128*1024*1024);  // 3*HID*Cc
    int8_t* qC0  = qEnc + (size_t)3*HID*Cc;                // 3*HID*HID
    int8_t* qC1  = qC0  + (size_t)3*HID*HID;               // 3*HID*HID
    float*  invN = (float*)(qC1 + (size_t)3*HID*HID);      // [3*HID]

    // ---- per-row weight quantization (1 wave/row; 3072 rows)
    quant_rows<<<768, 256, 0, stream>>>(enc_w, cell_w, qEnc, qC0, qC1, invN);

    // ---- conv + BN + LIF -> spk1 (= X[0:16MB]); zero out2 for the fused mean
    conv_bn_lif<<<(Bb*Lx*Cc/4 + 255)/256, 256, 0, stream>>>(x, cw, cb, g, be, mu, var, X);
    zero_out<<<(Bb*HID + 255)/256, 256, 0, stream>>>(out2, Bb*HID);

    // ---- full-problem trunk, one dispatch per layer (1024 blocks, XCD-decoded)
    gemm_lif<Cc,  false><<<1024, 512, 0, stream>>>(X, qEnc, invN,         enc_b,
                                                   Y, nullptr, nullptr);
    gemm_lif<HID, false><<<1024, 512, 0, stream>>>(Y, qC0,  invN + HID,   cell_b,
                                                   X, nullptr, nullptr);
    gemm_lif<HID, true ><<<1024, 512, 0, stream>>>(X, qC1,  invN + 2*HID, cell_b + HID,
                                                   nullptr, out1, out2);
}

// Round 16
// 418.205 us; speedup vs baseline: 1.1278x; 1.1278x over previous
//
#include <hip/hip_runtime.h>
#include <hip/hip_bf16.h>
#include <stdint.h>

#define Bb 32
#define Lx 512
#define Cc 256
#define Tt 4
#define HID 1024
#define RR (Bb*Lx)          // 16384 logical rows (b*L+l)
#define MRf (RR*Tt)         // 65536 interleaved rows (r*4+t)

typedef int i32x4 __attribute__((ext_vector_type(4)));

// ---------------- async global->LDS, 16B per lane
__device__ __forceinline__ void gl16(const void* g, void* l) {
    __builtin_amdgcn_global_load_lds(
        (const __attribute__((address_space(1))) unsigned int*)g,
        (__attribute__((address_space(3))) unsigned int*)l, 16, 0, 0);
}
__device__ __forceinline__ void blockbar() {
    asm volatile("" ::: "memory");
    __builtin_amdgcn_s_barrier();
    asm volatile("" ::: "memory");
}

// ---------------- per-row weight quantization: w*2^s_row = i1*2^14 + i2*2^7 + i3
// One wave per output row (exact fixed point; per-row pow2 scale).
__global__ void quant_rows(const float* __restrict__ enc_w,
                           const float* __restrict__ cell_w,
                           int8_t* __restrict__ qEnc, int8_t* __restrict__ qC0,
                           int8_t* __restrict__ qC1, float* __restrict__ invN) {
    const int gw   = (blockIdx.x * blockDim.x + threadIdx.x) >> 6;  // 0..3071
    const int lane = threadIdx.x & 63;
    const int mat  = gw >> 10;           // 0 enc, 1 cell0, 2 cell1
    const int row  = gw & 1023;
    const int Kk   = (mat == 0) ? Cc : HID;
    const float* w = (mat == 0) ? enc_w + (size_t)row * Cc
                                : cell_w + (size_t)(mat-1)*HID*HID + (size_t)row * HID;
    int8_t* q = ((mat == 0) ? qEnc : (mat == 1 ? qC0 : qC1)) + (size_t)row * Kk;
    const size_t nElem = (size_t)HID * Kk;

    float m = 0.0f;
    for (int k = lane; k < Kk; k += 64) m = fmaxf(m, fabsf(w[k]));
    #pragma unroll
    for (int o = 32; o; o >>= 1) m = fmaxf(m, __shfl_xor(m, o));
    m = fmaxf(m, 1e-20f);
    float sp = exp2f(floorf(log2f(126.0f * 16384.0f / m)));
    if (m * sp > 126.0f * 16384.0f) sp *= 0.5f;     // guard log2 boundary
    if (lane == 0) invN[mat*HID + row] = 1.0f / sp;
    for (int k = lane; k < Kk; k += 64) {
        float v  = rintf(w[k] * sp);                // |v| <= 126*2^14, integer-exact in f32
        float i1 = rintf(v * (1.0f/16384.0f));      // |i1| <= 126
        float r1 = v - i1 * 16384.0f;               // |r1| <= 2^13, exact
        float i2 = rintf(r1 * (1.0f/128.0f));       // |i2| <= 64
        float r2 = r1 - i2 * 128.0f;                // |r2| <= 64, exact
        q[k]           = (int8_t)i1;
        q[nElem + k]   = (int8_t)i2;
        q[2*nElem + k] = (int8_t)r2;
    }
}

__global__ void zero_out(float* p, int n) {
    int i = blockIdx.x * 256 + threadIdx.x;
    if (i < n) p[i] = 0.0f;
}

// ---------------- Stage 1: conv(K=3 over L) + BN + LIF -> i8 spikes, rows r*4+t
__global__ void conv_bn_lif(const float* __restrict__ x,
                            const float* __restrict__ cw, const float* __restrict__ cb,
                            const float* __restrict__ g,  const float* __restrict__ be,
                            const float* __restrict__ mu, const float* __restrict__ var,
                            int8_t* __restrict__ spk) {   // [RR*4][Cc]
    int idx = blockIdx.x * blockDim.x + threadIdx.x;      // over B*L*C/4
    if (idx >= Bb*Lx*Cc/4) return;
    int bl = idx / (Cc/4);
    int c4 = (idx % (Cc/4)) * 4;
    int l  = bl % Lx;
    float4 x0 = *(const float4*)(x + (size_t)bl*Cc + c4);
    float4 xm = (l > 0)    ? *(const float4*)(x + (size_t)bl*Cc + c4 - Cc) : float4{0,0,0,0};
    float4 xp = (l < Lx-1) ? *(const float4*)(x + (size_t)bl*Cc + c4 + Cc) : float4{0,0,0,0};
    float v0=0, v1=0, v2=0, v3=0;
    #pragma unroll
    for (int t = 0; t < Tt; ++t) {
        float w0 = cw[t*3+0], w1 = cw[t*3+1], w2 = cw[t*3+2];
        float inv = g[t] / sqrtf(var[t] + 1e-5f);
        float off = (cb[t] - mu[t]) * inv + be[t];
        float y0 = (w0*xm.x + w1*x0.x + w2*xp.x) * inv + off;
        float y1 = (w0*xm.y + w1*x0.y + w2*xp.y) * inv + off;
        float y2 = (w0*xm.z + w1*x0.z + w2*xp.z) * inv + off;
        float y3 = (w0*xm.w + w1*x0.w + w2*xp.w) * inv + off;
        v0 = v0 + (y0 - v0)*0.5f;  v1 = v1 + (y1 - v1)*0.5f;
        v2 = v2 + (y2 - v2)*0.5f;  v3 = v3 + (y3 - v3)*0.5f;
        float s0 = (v0 >= 1.0f) ? 1.0f : 0.0f;  float s1 = (v1 >= 1.0f) ? 1.0f : 0.0f;
        float s2 = (v2 >= 1.0f) ? 1.0f : 0.0f;  float s3 = (v3 >= 1.0f) ? 1.0f : 0.0f;
        uchar4 pk = { (uint8_t)s0, (uint8_t)s1, (uint8_t)s2, (uint8_t)s3 };
        *(uchar4*)(spk + (size_t)(bl*4 + t)*Cc + c4) = pk;
        v0 *= (1.0f - s0);  v1 *= (1.0f - s1);  v2 *= (1.0f - s2);  v3 *= (1.0f - s3);
    }
}

// ---------------- i8 3-pass GEMM, deep pipeline + LIF epilogue (+ fused L-mean)
// Tile 256x256, BK=64, 8 waves (2M x 4N), wave tile 128x64 (acc[8][4]=128 AGPR).
// 4 LDS bufs x 32KB; prefetch 3; counted vmcnt(8) (never 0 steady); ONE barrier/tile.
// At the measured LDS roofline: matrix 1307 cyc/tile vs LDS ~1300-1450 -> util ~47%.
// acc = (acc1*128 + acc2)*128 + acc3 exact in i32 (|acc| < 2^31, per-row scale).
template<int K, bool FINAL>
__global__ __launch_bounds__(512, 2)
void gemm_lif(const int8_t* __restrict__ A,
              const int8_t* __restrict__ Wq,      // [3 comps][HID][K]
              const float* __restrict__ invN,     // [HID] per-row 2^-s
              const float* __restrict__ bias,
              int8_t* __restrict__ spk_out, float* __restrict__ out_mean,
              float* __restrict__ out_sum) {
    constexpr int KT  = K / 64;           // tiles per component pass
    constexpr int NKT = 3 * KT;           // three fixed-point component passes
    __shared__ int8_t lds[4 * 32768];     // 4 bufs x (A 16KB + B 16KB)

    const int tid  = threadIdx.x;
    const int lane = tid & 63;
    const int wid  = tid >> 6;
    const int wm   = wid >> 2;        // 0..1
    const int wn   = wid & 3;         // 0..3
    // XCD-chunked decode (1024 blocks): xcd = bid&7 owns 32 m-panels; within an
    // XCD, n varies fastest (4 n-blocks reuse one L2-resident A panel).
    const int bid  = blockIdx.x;
    const int idx_ = bid >> 3;                     // 0..127
    const int n0   = (idx_ & 3) * 256;
    const int m0   = ((bid & 7) * 32 + (idx_ >> 2)) * 256;
    const int fr   = lane & 15;
    const int lq   = lane >> 4;
    const int swq  = (lq ^ ((fr >> 1) & 3)) * 16;   // conflict-free phys byte slot in 64B row
    const int srow = tid >> 2;                      // staging row (0..127)
    const int sl   = (tid & 3) ^ ((srow >> 1) & 3); // pre-swizzled source slot

    i32x4 acc[8][4] = {};

    // ---- stage one 64B-K tile (A 256rows + B 256rows) into buf: 4 gl16/thread
    auto stage = [&](int t, int8_t* buf) {
        const int8_t* Wc = Wq + (size_t)(t / KT) * HID * K;
        const int ko = (t % KT) * 64;
        gl16(A  + (size_t)(m0 +       srow) * K + ko + sl*16, buf +         tid*16);
        gl16(A  + (size_t)(m0 + 128 + srow) * K + ko + sl*16, buf +  8192 + tid*16);
        gl16(Wc + (size_t)(n0 +       srow) * K + ko + sl*16, buf + 16384 + tid*16);
        gl16(Wc + (size_t)(n0 + 128 + srow) * K + ko + sl*16, buf + 24576 + tid*16);
    };

    // ---- prologue: stage tiles 0,1,2 into bufs 0,1,2
    stage(0, &lds[0]);
    stage(1, &lds[32768]);
    stage(2, &lds[65536]);

    #pragma unroll 1
    for (int kt = 0; kt < NKT; ++kt) {
        if (kt == KT || kt == 2*KT) {     // component boundary: shift accumulated value
            #pragma unroll
            for (int i = 0; i < 8; ++i)
                #pragma unroll
                for (int j = 0; j < 4; ++j)
                    acc[i][j] *= 128;
        }
        if (kt < NKT-2)       asm volatile("s_waitcnt vmcnt(8)" ::: "memory");
        else if (kt == NKT-2) asm volatile("s_waitcnt vmcnt(4)" ::: "memory");
        else                  asm volatile("s_waitcnt vmcnt(0)" ::: "memory");
        blockbar();                       // tile kt landed for all waves

        const int cb = (kt & 3) * 32768;

        // ---- fragment reads (af first: first MFMA cluster's operands land first)
        i32x4 af[8], bf[4];
        #pragma unroll
        for (int i = 0; i < 8; ++i)
            af[i] = *(const i32x4*)&lds[cb + (wm*128 + i*16 + fr)*64 + swq];
        #pragma unroll
        for (int j = 0; j < 4; ++j)
            bf[j] = *(const i32x4*)&lds[cb + 16384 + (wn*64 + j*16 + fr)*64 + swq];

        // ---- staging sweeps for tile kt+3 (buffer (kt-1)&3: readers retired pre-barrier)
        if (kt + 3 < NKT) stage(kt + 3, &lds[((kt + 3) & 3) * 32768]);

        // ---- 32 MFMA; compiler inserts counted lgkm waits per cluster
        __builtin_amdgcn_s_setprio(1);
        #pragma unroll
        for (int i = 0; i < 8; ++i)
            #pragma unroll
            for (int j = 0; j < 4; ++j)
                acc[i][j] = __builtin_amdgcn_mfma_i32_16x16x64_i8(af[i], bf[j], acc[i][j], 0, 0, 0);
        __builtin_amdgcn_s_setprio(0);
    }

    // ---- epilogue: per-lane LIF over 4 acc regs (= 4 timesteps of one row)
    float bs[4], iv[4], msum[4] = {0,0,0,0};
    #pragma unroll
    for (int j = 0; j < 4; ++j) {
        int n = n0 + wn*64 + j*16 + fr;
        bs[j] = bias[n];
        iv[j] = invN[n];
    }
    const int rowq = lq * 4;
    #pragma unroll
    for (int i = 0; i < 8; ++i) {
        int rowLocal = m0 + wm*128 + i*16 + rowq;   // t=0 row; rows rowLocal..+3 = t 0..3
        int r = rowLocal >> 2;
        #pragma unroll
        for (int j = 0; j < 4; ++j) {
            int n = n0 + wn*64 + j*16 + fr;
            float v = 0.0f, ssum = 0.0f;
            #pragma unroll
            for (int t = 0; t < 4; ++t) {
                float xv = (float)acc[i][j][t] * iv[j] + bs[j];
                v = v + (xv - v) * 0.5f;
                float s = (v >= 1.0f) ? 1.0f : 0.0f;
                if constexpr (FINAL) ssum += s;
                else spk_out[(size_t)(rowLocal + t) * HID + n] = (int8_t)s;
                v = v * (1.0f - s);
            }
            if constexpr (FINAL) {
                out_mean[(size_t)r * HID + n] = ssum * 0.25f;
                msum[j] += ssum;            // integer <= 4, exact
            }
        }
    }
    if constexpr (FINAL) {
        // fused mean over L: reduce msum over lq (shfl) -> one dyadic atomicAdd per (fr,j).
        // All partials are multiples of 2^-11 and < 2 -> exact f32, order-independent.
        const int b = m0 >> 11;             // all 64 r's of this block share b
        #pragma unroll
        for (int j = 0; j < 4; ++j) {
            float v = msum[j];
            v += __shfl_xor(v, 16);
            v += __shfl_xor(v, 32);
            if (lq == 0) {
                int n = n0 + wn*64 + j*16 + fr;
                atomicAdd(out_sum + (size_t)b * HID + n, v * (0.25f / 512.0f));
            }
        }
    }
}

extern "C" void kernel_launch(void* const* d_in, const int* in_sizes, int n_in,
                              void* d_out, int out_size, void* d_ws, size_t ws_size,
                              hipStream_t stream) {
    const float* x      = (const float*)d_in[0];
    const float* cw     = (const float*)d_in[1];
    const float* cb     = (const float*)d_in[2];
    const float* g      = (const float*)d_in[3];
    const float* be     = (const float*)d_in[4];
    const float* mu     = (const float*)d_in[5];
    const float* var    = (const float*)d_in[6];
    const float* enc_w  = (const float*)d_in[7];
    const float* enc_b  = (const float*)d_in[8];
    const float* cell_w = (const float*)d_in[9];
    const float* cell_b = (const float*)d_in[10];

    float* out1 = (float*)d_out;                    // [RR][HID]
    float* out2 = out1 + (size_t)RR * HID;          // [B][HID]

    // ---- ws layout (~135 MB; 144 MB proven available)
    uint8_t* ws = (uint8_t*)d_ws;
    int8_t* X = (int8_t*)ws;                               // 64 MB (spk1 16MB -> layer2 out)
    int8_t* Y = (int8_t*)(ws + (size_t)64*1024*1024);      // 64 MB (layer1 out)
    int8_t* qEnc = (int8_t*)(ws + (size_t)128*1024*1024);  // 3*HID*Cc
    int8_t* qC0  = qEnc + (size_t)3*HID*Cc;                // 3*HID*HID
    int8_t* qC1  = qC0  + (size_t)3*HID*HID;               // 3*HID*HID
    float*  invN = (float*)(qC1 + (size_t)3*HID*HID);      // [3*HID]

    // ---- per-row weight quantization (1 wave/row; 3072 rows; 768 blocks)
    quant_rows<<<768, 256, 0, stream>>>(enc_w, cell_w, qEnc, qC0, qC1, invN);

    // ---- conv + BN + LIF -> spk1 (= X[0:16MB]); zero out2 for the fused mean
    conv_bn_lif<<<(Bb*Lx*Cc/4 + 255)/256, 256, 0, stream>>>(x, cw, cb, g, be, mu, var, X);
    zero_out<<<(Bb*HID + 255)/256, 256, 0, stream>>>(out2, Bb*HID);

    // ---- full-problem trunk, one dispatch per layer (1024 blocks, XCD-decoded)
    gemm_lif<Cc,  false><<<1024, 512, 0, stream>>>(X, qEnc, invN,        enc_b,
                                                   Y, nullptr, nullptr);
    gemm_lif<HID, false><<<1024, 512, 0, stream>>>(Y, qC0,  invN + HID,  cell_b,
                                                   X, nullptr, nullptr);
    gemm_lif<HID, true ><<<1024, 512, 0, stream>>>(X, qC1,  invN + 2*HID, cell_b + HID,
                                                   nullptr, out1, out2);
}